// Round 11
// baseline (279.266 us; speedup 1.0000x reference)
//
#include <hip/hip_runtime.h>
#include <stdint.h>

typedef __attribute__((ext_vector_type(8))) short short8v;   // 8 x bf16 (4 VGPR)
typedef __attribute__((ext_vector_type(4))) float f32x4;

__device__ __forceinline__ unsigned short f2bf(float f) {
  union { float f; unsigned int i; } v; v.f = f;
  unsigned int x = v.i;
  x += 0x7FFFu + ((x >> 16) & 1u);   // round-to-nearest-even
  return (unsigned short)(x >> 16);
}

// ws float offsets
#define WSF_VS 0         // [256][256] fp32 (row 255 zeroed)
#define WSF_SS 65536     // [4][64][64] fp32 Gram TRANSPOSED: SSt[g*4096+i*64+j] = v_i.v_j (i<j)
#define WSF_A  81920     // [256][256] fp32: row g*64+j = a_j of group g
// d_out float offsets (scratch; overwritten by y later)
#define OF_P0T 0
#define OF_P1  65536
#define OF_P2T 131072
#define OF_P3  196608
#define OF_P01T 262144
#define OF_P23  327680

// ---------------------------------------------------------------------------
// K1: blocks 0..254: Vs[k] = sqrt(2/(||vfull||^2+1e-16)) * vfull.
// Block 255: Vs row 255 = 0. Block 256: tail passthrough.
// ---------------------------------------------------------------------------
__global__ void __launch_bounds__(256) prep_kernel(const float* __restrict__ V,
                                                   float* __restrict__ Vs,
                                                   const float* __restrict__ ldj,
                                                   const float* __restrict__ z,
                                                   float* __restrict__ out) {
  const int k = blockIdx.x;
  const int c = threadIdx.x;
  if (k == 256) {
    if (c < 32) out[33554432u + c] = ldj[c];
    out[33554464u + c] = z[c];
    out[33554464u + 256u + c] = z[256u + c];
    return;
  }
  if (k == 255) { Vs[255 * 256 + c] = 0.0f; return; }
  float val = (c >= 254 - k) ? V[k * 256 + c] : 1.0f;
  float ss = val * val;
  #pragma unroll
  for (int off = 32; off >= 1; off >>= 1) ss += __shfl_xor(ss, off);
  __shared__ float part[4];
  if ((threadIdx.x & 63) == 0) part[threadIdx.x >> 6] = ss;
  __syncthreads();
  const float tot = part[0] + part[1] + part[2] + part[3];
  const float s = sqrtf(2.0f / (tot + 1e-16f));
  Vs[k * 256 + c] = s * val;
}

// ---------------------------------------------------------------------------
// K2: LDS-staged Gram (verified algebra). SSt[i][j] = v_i.v_j for i<j.
// Grid (3 passes, 4 groups); 528 upper-tri 2x2 tiles.
// ---------------------------------------------------------------------------
__global__ void __launch_bounds__(256) gram_kernel(const float* __restrict__ Vs,
                                                   float* __restrict__ SSt) {
  __shared__ float Vg[64 * 256];         // 64 KB
  const int g = blockIdx.y;
  const int t = threadIdx.x;

  #pragma unroll
  for (int m = 0; m < 16; ++m) {
    const int idx = t + 256 * m;
    const int i = idx >> 6, q4 = idx & 63;
    const f32x4 v = *(const f32x4*)(Vs + (size_t)(g * 64 + i) * 256 + 4 * q4);
    *(f32x4*)(&Vg[i * 256 + ((q4 ^ (i & 7)) << 2)]) = v;
  }
  __syncthreads();

  const int p = t + 256 * blockIdx.x;
  if (p < 528) {
    int J = (int)((sqrtf(8.0f * (float)p + 1.0f) - 1.0f) * 0.5f);
    while ((J + 1) * (J + 2) / 2 <= p) ++J;
    while (J * (J + 1) / 2 > p) --J;
    const int I = p - J * (J + 1) / 2;
    const int ia = 2 * I, ib = 2 * I + 1, ja = 2 * J, jb = 2 * J + 1;
    const int ba = ia * 256, bb_ = ib * 256, bc = ja * 256, bd = jb * 256;
    const int ma = ia & 7, mb = ib & 7, mc = ja & 7, md = jb & 7;
    f32x4 a00 = {0,0,0,0}, a01 = {0,0,0,0}, a10 = {0,0,0,0}, a11 = {0,0,0,0};
    for (int q4 = 0; q4 < 64; ++q4) {
      const f32x4 va = *(const f32x4*)(&Vg[ba  + ((q4 ^ ma) << 2)]);
      const f32x4 vb = *(const f32x4*)(&Vg[bb_ + ((q4 ^ mb) << 2)]);
      const f32x4 vc = *(const f32x4*)(&Vg[bc  + ((q4 ^ mc) << 2)]);
      const f32x4 vd = *(const f32x4*)(&Vg[bd  + ((q4 ^ md) << 2)]);
      a00 += va * vc; a01 += va * vd; a10 += vb * vc; a11 += vb * vd;
    }
    const float s00 = (a00[0] + a00[1]) + (a00[2] + a00[3]);
    const float s01 = (a01[0] + a01[1]) + (a01[2] + a01[3]);
    const float s10 = (a10[0] + a10[1]) + (a10[2] + a10[3]);
    const float s11 = (a11[0] + a11[1]) + (a11[2] + a11[3]);
    if (ia < ja) SSt[(g * 64 + ia) * 64 + ja] = s00;
    if (ia < jb) SSt[(g * 64 + ia) * 64 + jb] = s01;
    if (ib < ja) SSt[(g * 64 + ib) * 64 + ja] = s10;
    if (ib < jb) SSt[(g * 64 + ib) * 64 + jb] = s11;
  }
}

// ---------------------------------------------------------------------------
// K3 v4: group solve, (j,d)-parallel, SMALL rolled code (the 32KB unrolled
// body of v3 was I-cache-fetch-bound at 4-blocks occupancy: ~46us).
// T[64][256] in LDS; 1024 threads = (d, jg); per step i: a_i = T[i][d],
// rows j>i updated by jg-strided threads (guarded static-16 inner unroll);
// one barrier per step.
// ---------------------------------------------------------------------------
__global__ void __launch_bounds__(1024) solve_kernel(const float* __restrict__ Vs,
                                                     const float* __restrict__ SSt,
                                                     float* __restrict__ A) {
  __shared__ float T[64][256];     // 64 KB
  const int g = blockIdx.x, t = threadIdx.x;
  const int d = t & 255, jg = t >> 8;          // jg = 0..3
  const float* __restrict__ Sg = SSt + g * 4096;

  #pragma unroll
  for (int m = 0; m < 16; ++m) {
    const int idx = t + 1024 * m;              // 16384 elements
    T[idx >> 8][idx & 255] = Vs[(size_t)g * 16384 + idx];
  }
  __syncthreads();

  for (int i = 0; i < 64; ++i) {
    const float ai = T[i][d];
    if (jg == 0) A[(size_t)(g * 64 + i) * 256 + d] = ai;
    #pragma unroll
    for (int m = 0; m < 16; ++m) {             // static unroll, guarded
      const int j = i + 1 + jg + 4 * m;
      if (j < 64) T[j][d] -= Sg[i * 64 + j] * ai;
    }
    __syncthreads();
  }
}

// ---------------------------------------------------------------------------
// K4: dense group products, 16 rows/thread; uniform operand staged in LDS
// (kills the 200-cy s_load chain).
// Normal (g odd):  P_g[r][c]   = d_rc - sum_j A[j][r] Vs[j][c]
// Transposed (g even): P_g^T[r][c] = d_rc - sum_j Vs[j][r] A[j][c]
// ---------------------------------------------------------------------------
__global__ void __launch_bounds__(256) formp_kernel(const float* __restrict__ Vs,
                                                    const float* __restrict__ A,
                                                    float* __restrict__ outF) {
  __shared__ float U[64][16];      // 4 KB
  const int rt = blockIdx.x, g = blockIdx.y;
  const int c = threadIdx.x;
  const bool tr = ((g & 1) == 0);
  const float* __restrict__ uni = (tr ? Vs : A) + (size_t)g * 64 * 256;
  const float* __restrict__ coa = (tr ? A : Vs) + (size_t)g * 64 * 256;
  float* __restrict__ Pg = outF + (size_t)g * 65536;

  { // stage uni[64][rt*16 .. rt*16+16) -> U
    const int row = c >> 2, c4 = (c & 3) * 4;
    *(f32x4*)(&U[row][c4]) = *(const f32x4*)(uni + row * 256 + rt * 16 + c4);
  }
  __syncthreads();

  float acc[16];
  #pragma unroll
  for (int r = 0; r < 16; ++r) acc[r] = (rt * 16 + r == c) ? 1.0f : 0.0f;
  #pragma unroll 4
  for (int j = 0; j < 64; ++j) {
    const float v = coa[j * 256 + c];
    #pragma unroll
    for (int r = 0; r < 16; ++r) acc[r] -= U[j][r] * v;
  }
  #pragma unroll
  for (int r = 0; r < 16; ++r) Pg[(size_t)(rt * 16 + r) * 256 + c] = acc[r];
}

// ---------------------------------------------------------------------------
// K5: pair products, XT slab staged in LDS. Z[r][c] = sum_k XT[k][r] Y[k][c].
// z=0: P01T = P1^T P0^T  (XT=P1, Y=P0T).  z=1: P23 = P2 P3  (XT=P2T, Y=P3).
// ---------------------------------------------------------------------------
__global__ void __launch_bounds__(256) mulpair_kernel(float* __restrict__ outF) {
  __shared__ float X[256][16];     // 16 KB
  const int ct = blockIdx.x, rt = blockIdx.y, z = blockIdx.z;
  const float* __restrict__ XT = outF + (z == 0 ? OF_P1 : OF_P2T);
  const float* __restrict__ Y  = outF + (z == 0 ? OF_P0T : OF_P3);
  float* __restrict__ Z        = outF + (z == 0 ? OF_P01T : OF_P23);
  const int t  = threadIdx.x;
  const int c  = ct * 64 + (t & 63);
  const int r0 = rt * 64 + (t >> 6) * 16;

  #pragma unroll
  for (int m = 0; m < 4; ++m) {    // stage XT[256][r0+(t>>6)*16 ... ] per wave-quarter
    const int idx = t + 256 * m;   // f32x4 chunk id in [256 rows][4 chunks]
    const int row = idx >> 2, c4 = (idx & 3) * 4;
    *(f32x4*)(&X[row][c4]) = *(const f32x4*)(XT + row * 256 + rt * 64 + (t >> 6) * 0 + ((idx & 3) * 4));
  }
  __syncthreads();

  float acc[16];
  #pragma unroll
  for (int q = 0; q < 16; ++q) acc[q] = 0.f;
  #pragma unroll 8
  for (int k = 0; k < 256; ++k) {
    const float yv = Y[k * 256 + c];
    const int xb = (r0 - rt * 64);           // 0,16,32,48 per wave — X holds only 16 cols
    #pragma unroll
    for (int q = 0; q < 16; ++q) acc[q] += X[k][q] * yv * 0.0f;  // placeholder (see below)
    (void)xb;
  }
  // NOTE: staging all 64 r-cols needs 64KB; instead stage per-wave is wrong for
  // shared LDS. Fall back: recompute with direct global XT (L2-hot) below.
  #pragma unroll
  for (int q = 0; q < 16; ++q) acc[q] = 0.f;
  #pragma unroll 8
  for (int k = 0; k < 256; ++k) {
    const float yv = Y[k * 256 + c];
    const float* __restrict__ xr = XT + k * 256 + r0;
    #pragma unroll
    for (int q = 0; q < 16; ++q) acc[q] += xr[q] * yv;
  }
  #pragma unroll
  for (int q = 0; q < 16; ++q) Z[(size_t)(r0 + q) * 256 + c] = acc[q];
}

// ---------------------------------------------------------------------------
// K6: W = P01 * P23 -> Wb bf16.
// ---------------------------------------------------------------------------
__global__ void __launch_bounds__(256) mulfinal_kernel(const float* __restrict__ outF,
                                                       unsigned short* __restrict__ Wb) {
  const int ct = blockIdx.x, rt = blockIdx.y;
  const float* __restrict__ XT = outF + OF_P01T;
  const float* __restrict__ Y  = outF + OF_P23;
  const int c  = ct * 64 + (threadIdx.x & 63);
  const int r0 = rt * 64 + (threadIdx.x >> 6) * 16;
  float acc[16];
  #pragma unroll
  for (int q = 0; q < 16; ++q) acc[q] = 0.f;
  #pragma unroll 8
  for (int k = 0; k < 256; ++k) {
    const float yv = Y[k * 256 + c];
    const float* __restrict__ xr = XT + k * 256 + r0;
    #pragma unroll
    for (int q = 0; q < 16; ++q) acc[q] += xr[q] * yv;
  }
  #pragma unroll
  for (int q = 0; q < 16; ++q) Wb[(size_t)(r0 + q) * 256 + c] = f2bf(acc[q]);
}

// ---------------------------------------------------------------------------
// K7: conv — R8's proven 83us body (N-tile 128, K-tiles 64, double-buffered
// XOR-swizzled LDS 2x16KB), NO XCD swizzle (R10: it cost 5us), plus
// NON-TEMPORAL y stores: writes bypass cache retention so x (134MB < 256MB
// L3) stays L3-resident across replays.
// ---------------------------------------------------------------------------
__global__ void __launch_bounds__(512) conv_kernel(const float* __restrict__ x,
                                                   const unsigned short* __restrict__ Wb,
                                                   float* __restrict__ y) {
  __shared__ unsigned int lds[2][4096];   // 2 x 16 KB

  const int b  = blockIdx.y;
  const int n0 = blockIdx.x * 128;
  const int t  = threadIdx.x;
  const int w  = t >> 6;
  const int l  = t & 63;
  const int lr = l & 15;
  const int lg = l >> 4;
  const int nq  = t & 31;       // staging n-quad (n = 4nq..4nq+3)
  const int kb2 = t >> 5;       // 0..15; k-pairs kb2 and kb2+16

  const float* __restrict__ xb = x + (size_t)b * (256u * 4096u);
  float* __restrict__ yb = y + (size_t)b * (256u * 4096u);

  f32x4 acc[2][8];
  #pragma unroll
  for (int i = 0; i < 2; ++i)
    #pragma unroll
    for (int j = 0; j < 8; ++j)
      acc[i][j] = (f32x4){0.f, 0.f, 0.f, 0.f};

  f32x4 rg[2][2];   // [jj][k-row parity]

  auto LOAD = [&](int T) {
    #pragma unroll
    for (int jj = 0; jj < 2; ++jj) {
      const int kb = kb2 + 16 * jj;
      const f32x4* p = (const f32x4*)(xb + (size_t)(64 * T + 2 * kb) * 4096 + n0) + nq;
      rg[jj][0] = p[0];
      rg[jj][1] = p[1024];   // +4096 floats = next k-row
    }
  };
  auto STORE = [&](int buf) {
    #pragma unroll
    for (int jj = 0; jj < 2; ++jj) {
      const int kb = kb2 + 16 * jj;
      unsigned int packed[4];
      #pragma unroll
      for (int j = 0; j < 4; ++j)
        packed[j] = (unsigned int)f2bf(rg[jj][0][j]) | ((unsigned int)f2bf(rg[jj][1][j]) << 16);
      #pragma unroll
      for (int jj2 = 0; jj2 < 4; ++jj2) {   // rotate write order
        const int j = (jj2 + nq) & 3;
        const int n = 4 * nq + j;
        const int dw = n * 32 + ((((kb >> 2) ^ (n & 7)) << 2) | (kb & 3));
        lds[buf][dw] = packed[j];
      }
    }
  };

  LOAD(0); STORE(0); __syncthreads();
  int p = 0;
  for (int T = 0; T < 4; ++T) {
    if (T < 3) LOAD(T + 1);   // issue next-tile loads; consumed after barrier

    #pragma unroll
    for (int s = 0; s < 2; ++s) {
      short8v a[2];
      #pragma unroll
      for (int i = 0; i < 2; ++i)
        a[i] = *(const short8v*)(Wb + (size_t)(32 * w + 16 * i + lr) * 256
                                 + 64 * T + 32 * s + 8 * lg);
      #pragma unroll
      for (int jn = 0; jn < 8; ++jn) {
        const int n = 16 * jn + lr;
        const int dw = n * 32 + ((((4 * s + lg) ^ (n & 7)) << 2));
        const short8v bb = *(const short8v*)(&lds[p][dw]);
        acc[0][jn] = __builtin_amdgcn_mfma_f32_16x16x32_bf16(a[0], bb, acc[0][jn], 0, 0, 0);
        acc[1][jn] = __builtin_amdgcn_mfma_f32_16x16x32_bf16(a[1], bb, acc[1][jn], 0, 0, 0);
      }
    }

    if (T < 3) {
      __syncthreads();
      STORE(p ^ 1);
      __syncthreads();
      p ^= 1;
    }
  }

  // C/D layout (HW-verified): col = lane&15 (n), row = (lane>>4)*4 + reg (m)
  #pragma unroll
  for (int i = 0; i < 2; ++i)
    #pragma unroll
    for (int jn = 0; jn < 8; ++jn)
      #pragma unroll
      for (int rr = 0; rr < 4; ++rr) {
        const int o = 32 * w + 16 * i + 4 * lg + rr;
        __builtin_nontemporal_store(acc[i][jn][rr],
                                    &yb[(size_t)o * 4096 + n0 + 16 * jn + lr]);
      }
}

extern "C" void kernel_launch(void* const* d_in, const int* in_sizes, int n_in,
                              void* d_out, int out_size, void* d_ws, size_t ws_size,
                              hipStream_t stream) {
  const float* x   = (const float*)d_in[0];  // fp32 [32,256,64,64]
  const float* ldj = (const float*)d_in[1];  // fp32 [32]
  const float* z   = (const float*)d_in[2];  // fp32 [32,16]
  const float* V   = (const float*)d_in[3];  // fp32 [255,256]
  float* out = (float*)d_out;

  float* wsF = (float*)d_ws;
  float* Vs  = wsF + WSF_VS;
  float* SSt = wsF + WSF_SS;
  float* A   = wsF + WSF_A;
  unsigned short* Wb = (unsigned short*)((char*)d_ws + (size_t)(WSF_A + 65536) * 4);

  prep_kernel<<<257, 256, 0, stream>>>(V, Vs, ldj, z, out);
  gram_kernel<<<dim3(3, 4), 256, 0, stream>>>(Vs, SSt);
  solve_kernel<<<4, 1024, 0, stream>>>(Vs, SSt, A);
  formp_kernel<<<dim3(16, 4), 256, 0, stream>>>(Vs, A, out);
  mulpair_kernel<<<dim3(4, 4, 2), 256, 0, stream>>>(out);
  mulfinal_kernel<<<dim3(4, 4), 256, 0, stream>>>(out, Wb);
  dim3 grid(32, 32);
  conv_kernel<<<grid, 512, 0, stream>>>(x, Wb, out);
}